// Round 8
// baseline (473.973 us; speedup 1.0000x reference)
//
#include <hip/hip_runtime.h>
#include <hip/hip_bf16.h>

#define N_NODES 20000
#define N_EDGES 250000
#define T_WIN   60
#define F_IN    16
#define HID     128
#define G4      512      // 4*HID
#define HEADS   4

// ---------------- ws layout (float offsets) ----------------
#define WPK_OFF    0            // 81920 ushort (LSTM W B-frags)
#define BIASC_OFF  40960        // 512
#define WPK2_OFF   41472        // 131072 ushort (GAT-lin W B-frags) = 65536 floats
#define BIASC2_OFF 107008       // 1024
#define H_OFF      108032       // 20000*128 ushort (bf16 h) = 1,280,000 floats
#define XL_OFF     1388032      // 20000*512 ushort = 5,120,000 floats
#define XR_OFF     6508032      // 20000*512 ushort
#define CNT_OFF    11628032     // 20000 ints
#define CNT2_OFF   11648032     // 20000 ints
#define BASE_OFF   11668032     // 20001 ints
#define SRT_OFF    11688033     // 250000 ints

typedef __attribute__((ext_vector_type(8))) short short8;
typedef __attribute__((ext_vector_type(8))) unsigned short ushort8;
typedef __attribute__((ext_vector_type(4))) float f32x4;
typedef __attribute__((ext_vector_type(4))) unsigned short ushortx4;

// fast activations: v_rcp_f32 (rel err ~2^-22) instead of IEEE divide
__device__ __forceinline__ float fsigmoid(float x) {
    return __builtin_amdgcn_rcpf(1.0f + __expf(-x));
}
__device__ __forceinline__ float ftanh(float x) {
    return fmaf(2.0f, __builtin_amdgcn_rcpf(1.0f + __expf(-2.0f * x)), -1.0f);
}

__device__ __forceinline__ unsigned short f2bf(float f) {
    unsigned u = __float_as_uint(f);
    u += 0x7FFFu + ((u >> 16) & 1u);   // RNE
    return (unsigned short)(u >> 16);
}
__device__ __forceinline__ float bf2f(unsigned short u) {
    return __uint_as_float((unsigned)u << 16);
}
__device__ __forceinline__ unsigned cvt_pk_bf16(float a, float b) {
    unsigned r;
    asm("v_cvt_pk_bf16_f32 %0, %1, %2" : "=v"(r) : "v"(a), "v"(b));
    return r;
}

// ---------------- pack LSTM W into MFMA B-fragment layout ----------------
// Wpk index = (((g*8+ht)*5+kt)*64 + lane)*8 + i
// element: k = kt*32 + (lane>>4)*8 + i ; col = g*128 + ht*16 + (lane&15)
// B[k][col] = k<128 ? Whh[col][k] : (k<144 ? Wih[col][k-128] : 0)
__global__ void pack_w_kernel(const float* __restrict__ Wih, const float* __restrict__ Whh,
                              const float* __restrict__ bih, const float* __restrict__ bhh,
                              unsigned short* __restrict__ wpk, float* __restrict__ biasc)
{
    int idx = blockIdx.x * 256 + threadIdx.x;
    if (idx < 81920) {
        int i  = idx & 7;
        int l  = (idx >> 3) & 63;
        int r  = idx >> 9;
        int kt = r % 5;
        int gh = r / 5;
        int ht = gh & 7;
        int g  = gh >> 3;
        int k   = kt * 32 + (l >> 4) * 8 + i;
        int col = g * 128 + ht * 16 + (l & 15);
        float v = 0.0f;
        if (k < 128)      v = Whh[col * 128 + k];
        else if (k < 144) v = Wih[col * 16 + (k - 128)];
        wpk[idx] = f2bf(v);
    }
    if (idx < G4) biasc[idx] = bih[idx] + bhh[idx];
}

// ---------------- pack GAT lin W (Wl|Wr -> [128 k][1024 cols]) into B-frags ----------------
__global__ void pack_w2_kernel(const float* __restrict__ Wl, const float* __restrict__ bl,
                               const float* __restrict__ Wr, const float* __restrict__ br,
                               unsigned short* __restrict__ wpk2, float* __restrict__ biasc2)
{
    int idx = blockIdx.x * 256 + threadIdx.x;
    if (idx < 131072) {
        int i  = idx & 7;
        int l  = (idx >> 3) & 63;
        int f  = idx >> 9;       // ht*4 + kt
        int kt = f & 3;
        int ht = f >> 2;
        int k   = kt * 32 + (l >> 4) * 8 + i;
        int col = ht * 16 + (l & 15);
        float v = (col < 512) ? Wl[col * 128 + k] : Wr[(col - 512) * 128 + k];
        wpk2[idx] = f2bf(v);
    }
    if (idx < 1024) biasc2[idx] = (idx < 512) ? bl[idx] : br[idx - 512];
}

// ---------------- LSTM: MFMA bf16, 32 nodes/block, 625 blocks (~2 blocks/CU) ----------------
// EXACT round-6 structure (XOR-swizzled ASTR=384 panel, __expf activations) with BMM 80->32.
// Time loop unroll 1 ON PURPOSE (r4: unroll 2 spilled ~96 MB to scratch).
#define BMM  32
#define ASTR 384

__global__ __launch_bounds__(512) void lstm_mfma_kernel(
    const float* __restrict__ x, const unsigned short* __restrict__ wpk,
    const float* __restrict__ biasc, unsigned short* __restrict__ hout)
{
    __shared__ __align__(16) unsigned char Abuf[2][BMM * ASTR];
    const int tid  = threadIdx.x;
    const int wave = tid >> 6;
    const int lane = tid & 63;
    const int n0   = blockIdx.x * BMM;

    {
        f32x4 z = {0.0f, 0.0f, 0.0f, 0.0f};
        unsigned char* ab = &Abuf[0][0];
        for (int i = tid; i < 2 * BMM * ASTR / 16; i += 512)
            *(f32x4*)&ab[i * 16] = z;
    }

    // persistent B-fragments: wave w owns hid cols [w*16, w*16+16) for all 4 gates
    short8 wf[4][5];
#pragma unroll
    for (int g = 0; g < 4; ++g)
#pragma unroll
        for (int kt = 0; kt < 5; ++kt)
            wf[g][kt] = *(const short8*)&wpk[((((g * 8 + wave) * 5) + kt) * 64 + lane) * 8];

    float bias[4];
#pragma unroll
    for (int g = 0; g < 4; ++g) bias[g] = biasc[g * 128 + wave * 16 + (lane & 15)];

    float c[2][4];
#pragma unroll
    for (int mt = 0; mt < 2; ++mt)
#pragma unroll
        for (int r = 0; r < 4; ++r) c[mt][r] = 0.0f;

    const int  xnode   = tid >> 2;          // 0..31 for tid<128
    const int  xq      = tid & 3;
    const bool xactive = (tid < BMM * 4);   // 128 threads stage x
    const int  xoff    = (256 + xq * 8) ^ ((xnode & 7) << 4);
    const int  colw    = wave * 16 + (lane & 15);
    const float* xptr  = &x[(size_t)(n0 + xnode) * (T_WIN * F_IN) + xq * 4];

    __syncthreads();

    if (xactive) {
        float4 v = *(const float4*)xptr;
        ushortx4 b;
        b.x = f2bf(v.x); b.y = f2bf(v.y); b.z = f2bf(v.z); b.w = f2bf(v.w);
        *(ushortx4*)&Abuf[0][xnode * ASTR + xoff] = b;
    }
    __syncthreads();

#pragma unroll 1
    for (int t = 0; t < T_WIN; ++t) {
        const int cur = t & 1;
        const int nxt = cur ^ 1;

        float4 xv = {0.0f, 0.0f, 0.0f, 0.0f};
        if (xactive && t + 1 < T_WIN) xv = *(const float4*)(xptr + (t + 1) * F_IN);

        // per-mt: ds_read -> 20 MFMA -> activation (act(mt) overlaps MFMA(mt+1))
#pragma unroll
        for (int mt = 0; mt < 2; ++mt) {
            const int row = mt * 16 + (lane & 15);
            const int rsw = (row & 7) << 4;
            short8 af[5];
#pragma unroll
            for (int kt = 0; kt < 5; ++kt)
                af[kt] = *(const short8*)&Abuf[cur][row * ASTR + ((kt * 64 + (lane >> 4) * 16) ^ rsw)];

            f32x4 ag[4];
#pragma unroll
            for (int g = 0; g < 4; ++g) {
                f32x4 a = {bias[g], bias[g], bias[g], bias[g]};
                ag[g] = a;
            }
#pragma unroll
            for (int kt = 0; kt < 5; ++kt)
#pragma unroll
                for (int g = 0; g < 4; ++g)
                    ag[g] = __builtin_amdgcn_mfma_f32_16x16x32_bf16(af[kt], wf[g][kt], ag[g], 0, 0, 0);

#pragma unroll
            for (int rp = 0; rp < 2; ++rp) {
                float hh[2];
#pragma unroll
                for (int r2 = 0; r2 < 2; ++r2) {
                    const int r = rp * 2 + r2;
                    float ig = fsigmoid(ag[0][r]);
                    float fg = fsigmoid(ag[1][r]);
                    float gg = ftanh(ag[2][r]);
                    float og = fsigmoid(ag[3][r]);
                    float cn = fg * c[mt][r] + ig * gg;
                    c[mt][r] = cn;
                    hh[r2] = og * ftanh(cn);
                }
                const unsigned pk = cvt_pk_bf16(hh[0], hh[1]);
                const int node0 = mt * 16 + (lane >> 4) * 4 + rp * 2;
                const int node1 = node0 + 1;
                if (t < T_WIN - 1) {
                    *(unsigned short*)&Abuf[nxt][node0 * ASTR + ((colw * 2) ^ ((node0 & 7) << 4))] =
                        (unsigned short)pk;
                    *(unsigned short*)&Abuf[nxt][node1 * ASTR + ((colw * 2) ^ ((node1 & 7) << 4))] =
                        (unsigned short)(pk >> 16);
                } else {
                    hout[(size_t)(n0 + node0) * HID + colw] = (unsigned short)pk;
                    hout[(size_t)(n0 + node1) * HID + colw] = (unsigned short)(pk >> 16);
                }
            }
        }

        if (xactive && t + 1 < T_WIN) {
            ushortx4 b;
            b.x = f2bf(xv.x); b.y = f2bf(xv.y); b.z = f2bf(xv.z); b.w = f2bf(xv.w);
            *(ushortx4*)&Abuf[nxt][xnode * ASTR + xoff] = b;
        }
        __syncthreads();
    }
}

// ---------------- GEMM2 (MFMA): [xl|xr] = h @ [Wl|Wr]^T + bias, bf16 in/out ----------------
#define G2_BM 64
__global__ __launch_bounds__(256) void gemm2_mfma_kernel(
    const unsigned short* __restrict__ hbf,   // [20000][128] bf16
    const unsigned short* __restrict__ wpk2,  // packed B-frags
    const float* __restrict__ biasc2,         // [1024]
    unsigned short* __restrict__ xl, unsigned short* __restrict__ xr)
{
    __shared__ __align__(16) unsigned char Hs[G2_BM * 256];  // [64 rows][128 bf16], XOR-swizzled
    const int tid  = threadIdx.x;
    const int wave = tid >> 6;
    const int lane = tid & 63;
    const int mb = blockIdx.x >> 2;
    const int nb = blockIdx.x & 3;     // 4 col-blocks of 256 (0,1 -> xl; 2,3 -> xr)
    const int n0 = mb * G2_BM;

#pragma unroll
    for (int q = 0; q < 4; ++q) {
        int fi = tid + q * 256;
        int node = fi >> 4;
        int kb = (fi & 15) * 16;
        ushort8 v = {0, 0, 0, 0, 0, 0, 0, 0};
        if (n0 + node < N_NODES) v = *(const ushort8*)&hbf[(size_t)(n0 + node) * HID + kb / 2];
        *(ushort8*)&Hs[node * 256 + (kb ^ ((node & 7) << 4))] = v;
    }
    __syncthreads();

    const int colt0 = nb * 16 + wave * 4;
    float bias4[4];
#pragma unroll
    for (int ct = 0; ct < 4; ++ct)
        bias4[ct] = biasc2[(colt0 + ct) * 16 + (lane & 15)];

    f32x4 acc[4][4];
#pragma unroll
    for (int mt = 0; mt < 4; ++mt)
#pragma unroll
        for (int ct = 0; ct < 4; ++ct) {
            f32x4 a = {bias4[ct], bias4[ct], bias4[ct], bias4[ct]};
            acc[mt][ct] = a;
        }

#pragma unroll
    for (int kt = 0; kt < 4; ++kt) {
        short8 wf[4];
#pragma unroll
        for (int ct = 0; ct < 4; ++ct)
            wf[ct] = *(const short8*)&wpk2[(((colt0 + ct) * 4 + kt) * 64 + lane) * 8];
        short8 af[4];
        const int kbyte = kt * 64 + (lane >> 4) * 16;
#pragma unroll
        for (int mt = 0; mt < 4; ++mt) {
            int row = mt * 16 + (lane & 15);
            af[mt] = *(const short8*)&Hs[row * 256 + (kbyte ^ ((row & 7) << 4))];
        }
#pragma unroll
        for (int mt = 0; mt < 4; ++mt)
#pragma unroll
            for (int ct = 0; ct < 4; ++ct)
                acc[mt][ct] = __builtin_amdgcn_mfma_f32_16x16x32_bf16(af[mt], wf[ct], acc[mt][ct], 0, 0, 0);
    }

    unsigned short* outp = (nb < 2) ? xl : xr;
    const int lcol = (nb & 1) * 256 + wave * 64 + (lane & 15);
#pragma unroll
    for (int mt = 0; mt < 4; ++mt)
#pragma unroll
        for (int ct = 0; ct < 4; ++ct)
#pragma unroll
            for (int r = 0; r < 4; ++r) {
                int row = n0 + mt * 16 + (lane >> 4) * 4 + r;
                if (row < N_NODES)
                    outp[(size_t)row * G4 + lcol + ct * 16] = f2bf(acc[mt][ct][r]);
            }
}

// ---------------- edge sort (counting sort by dst) ----------------
__global__ void count_kernel(const int* __restrict__ ei, int* __restrict__ cnt)
{
    int e = blockIdx.x * 256 + threadIdx.x;
    if (e < N_EDGES) {
        int dst = ei[N_EDGES + e];
        if (dst >= 0 && dst < N_NODES) atomicAdd(&cnt[dst], 1);
    }
}

__global__ void scan_kernel(const int* __restrict__ cnt, int* __restrict__ base)
{
    __shared__ int ps[256];
    const int tid = threadIdx.x;
    const int CH = (N_NODES + 255) / 256;
    int s = 0;
    for (int i = 0; i < CH; ++i) {
        int idx = tid * CH + i;
        if (idx < N_NODES) s += cnt[idx];
    }
    ps[tid] = s;
    __syncthreads();
    for (int off = 1; off < 256; off <<= 1) {
        int v = (tid >= off) ? ps[tid - off] : 0;
        __syncthreads();
        ps[tid] += v;
        __syncthreads();
    }
    int run = (tid > 0) ? ps[tid - 1] : 0;
    for (int i = 0; i < CH; ++i) {
        int idx = tid * CH + i;
        if (idx < N_NODES) { base[idx] = run; run += cnt[idx]; }
    }
    if (tid == 255) base[N_NODES] = ps[255];
}

__global__ void scatter_kernel(const int* __restrict__ ei, const int* __restrict__ base,
                               int* __restrict__ cnt2, int* __restrict__ srt)
{
    int e = blockIdx.x * 256 + threadIdx.x;
    if (e < N_EDGES) {
        int dst = ei[N_EDGES + e];
        int src = ei[e];
        if (dst >= 0 && dst < N_NODES) {
            int pos = base[dst] + atomicAdd(&cnt2[dst], 1);
            srt[pos] = src;
        }
    }
}

// ---------------- GATv2 aggregate: one wave per dst, online softmax (bf16 xl/xr) ----------------
__global__ __launch_bounds__(256) void gat_kernel(
    const unsigned short* __restrict__ xl, const unsigned short* __restrict__ xr,
    const float* __restrict__ att, const float* __restrict__ gbias,
    const float* __restrict__ Wp, const float* __restrict__ bp,
    const int* __restrict__ base, const int* __restrict__ srt,
    float* __restrict__ out)
{
    const int wave = threadIdx.x >> 6;
    const int lane = threadIdx.x & 63;
    const int dst = blockIdx.x * 4 + wave;
    if (dst >= N_NODES) return;

    ushort8 xr8 = *(const ushort8*)&xr[(size_t)dst * G4 + lane * 8];
    float xrv[8];
#pragma unroll
    for (int i = 0; i < 8; ++i) xrv[i] = bf2f(xr8[i]);
    float4 at0 = *(const float4*)&att[lane * 8];
    float4 at1 = *(const float4*)&att[lane * 8 + 4];
    float atv[8] = {at0.x, at0.y, at0.z, at0.w, at1.x, at1.y, at1.z, at1.w};

    float m = -INFINITY, d = 0.0f;
    float acc[8];
#pragma unroll
    for (int i = 0; i < 8; ++i) acc[i] = 0.0f;

    const int b0 = base[dst], b1 = base[dst + 1];
    for (int idx = b0; idx <= b1; ++idx) {
        int src = (idx < b1) ? srt[idx] : dst;
        ushort8 v8 = *(const ushort8*)&xl[(size_t)src * G4 + lane * 8];
        float xv[8];
#pragma unroll
        for (int i = 0; i < 8; ++i) xv[i] = bf2f(v8[i]);
        float p = 0.0f;
#pragma unroll
        for (int i = 0; i < 8; ++i) {
            float e = xv[i] + xrv[i];
            e = (e > 0.0f) ? e : 0.2f * e;
            p = fmaf(atv[i], e, p);
        }
        p += __shfl_xor(p, 1);
        p += __shfl_xor(p, 2);
        p += __shfl_xor(p, 4);
        p += __shfl_xor(p, 8);
        float mn = fmaxf(m, p);
        float scale = __expf(m - mn);
        float al = __expf(p - mn);
        d = d * scale + al;
#pragma unroll
        for (int i = 0; i < 8; ++i) acc[i] = fmaf(al, xv[i], acc[i] * scale);
        m = mn;
    }

    float inv = 1.0f / d;
    float o[8];
#pragma unroll
    for (int i = 0; i < 8; ++i) o[i] = acc[i] * inv;
#pragma unroll
    for (int i = 0; i < 8; ++i) {
        o[i] += __shfl_xor(o[i], 16);
        o[i] += __shfl_xor(o[i], 32);
    }
    const int c0 = (lane & 15) * 8;
    float psum = 0.0f;
#pragma unroll
    for (int i = 0; i < 8; ++i) {
        float s = 0.25f * o[i] + gbias[c0 + i];
        s = (s > 0.0f) ? s : (__expf(s) - 1.0f);
        psum = fmaf(s, Wp[c0 + i], psum);
    }
    psum += __shfl_xor(psum, 1);
    psum += __shfl_xor(psum, 2);
    psum += __shfl_xor(psum, 4);
    psum += __shfl_xor(psum, 8);
    if (lane == 0) out[dst] = psum + bp[0];
}

// ---------------- launch ----------------
extern "C" void kernel_launch(void* const* d_in, const int* in_sizes, int n_in,
                              void* d_out, int out_size, void* d_ws, size_t ws_size,
                              hipStream_t stream)
{
    const float* x        = (const float*)d_in[0];
    const int* ei         = (const int*)d_in[1];     // int32 per harness contract
    const float* Wih      = (const float*)d_in[2];
    const float* Whh      = (const float*)d_in[3];
    const float* bih      = (const float*)d_in[4];
    const float* bhh      = (const float*)d_in[5];
    const float* Wl       = (const float*)d_in[6];
    const float* bl       = (const float*)d_in[7];
    const float* Wr       = (const float*)d_in[8];
    const float* br       = (const float*)d_in[9];
    const float* att      = (const float*)d_in[10];
    const float* gbias    = (const float*)d_in[11];
    const float* Wp       = (const float*)d_in[12];
    const float* bp       = (const float*)d_in[13];
    float* out            = (float*)d_out;

    float* ws             = (float*)d_ws;
    unsigned short* wpk   = (unsigned short*)(ws + WPK_OFF);
    float* bsc            = ws + BIASC_OFF;
    unsigned short* wpk2  = (unsigned short*)(ws + WPK2_OFF);
    float* bsc2           = ws + BIASC2_OFF;
    unsigned short* h     = (unsigned short*)(ws + H_OFF);
    unsigned short* xlb   = (unsigned short*)(ws + XL_OFF);
    unsigned short* xrb   = (unsigned short*)(ws + XR_OFF);
    int* cnt    = (int*)(ws + CNT_OFF);
    int* cnt2   = (int*)(ws + CNT2_OFF);
    int* base   = (int*)(ws + BASE_OFF);
    int* srt    = (int*)(ws + SRT_OFF);

    hipMemsetAsync(cnt, 0, 2 * N_NODES * sizeof(int), stream);

    pack_w_kernel<<<320, 256, 0, stream>>>(Wih, Whh, bih, bhh, wpk, bsc);
    pack_w2_kernel<<<512, 256, 0, stream>>>(Wl, bl, Wr, br, wpk2, bsc2);
    count_kernel<<<(N_EDGES + 255) / 256, 256, 0, stream>>>(ei, cnt);
    scan_kernel<<<1, 256, 0, stream>>>(cnt, base);
    scatter_kernel<<<(N_EDGES + 255) / 256, 256, 0, stream>>>(ei, base, cnt2, srt);

    lstm_mfma_kernel<<<N_NODES / BMM, 512, 0, stream>>>(x, wpk, bsc, h);
    gemm2_mfma_kernel<<<((N_NODES + G2_BM - 1) / G2_BM) * 4, 256, 0, stream>>>(h, wpk2, bsc2, xlb, xrb);
    gat_kernel<<<(N_NODES + 3) / 4, 256, 0, stream>>>(xlb, xrb, att, gbias, Wp, bp, base, srt, out);
}